// Round 5
// baseline (249.563 us; speedup 1.0000x reference)
//
#include <hip/hip_runtime.h>

// VQ embedding, bf16-MFMA, packed uint argmin.
// z: (B=64, D=256, H=32, W=32) fp32; codebook: (K=1024, D=256) fp32.
// argmin_k ||z_n - c_k||^2 = argmin_k (1 + ||c_k||^2 - 2 z.c_k)   [shift keeps score > 0]
// Packed key: (float_bits(score) & 0xFFFFFC00) | k  -> uint min = argmin w/ first-index ties.
// Outputs (flat fp32): st[16777216] = chosen codebook row, indices[65536] as float,
// loss = 1.25 * (sum z^2 + sum (best_score - 1)).
//
// R5: evidence (R0/R2/R3 cluster at ~5.3 TB/s effective codebook-L2 read rate; time
// tracked B-traffic, occupancy+pipelining were nulls) says the kernel is bound by the
// L2 codebook stream. So: BM=128 rows/block -> 512 blocks -> B traffic 512->256 MB
// (halved), still zero duplication: each of 4 waves covers ALL 128 rows (a[8],
// acc[8][2]=64 AGPR) x its own 32-code quarter of each 128-code chunk. 16 MFMA per
// 2 B-loads (2x R4 density). B 1-deep prefetch only; A read in-place (R4 proved
// deeper pipelining null). ~170 unified regs -> 2 waves/SIMD under (256,2);
// LDS 64 KB tile -> 2 blocks/CU, grid 512 = exact fill. kt0 rotated by (blk&7)*128.

#define IDX_OFF  16777216
#define LOSS_OFF 16842752

typedef __bf16 bf16x8 __attribute__((ext_vector_type(8)));
typedef float  f32x4  __attribute__((ext_vector_type(4)));

// ---------------- Kernel 1: cb fp32 -> bf16 copy + (1 + row norm) ----------------
__global__ __launch_bounds__(256) void vq_prep(const float* __restrict__ cb,
                                               __bf16* __restrict__ cbh,
                                               float* __restrict__ sc1) {
    const int t = threadIdx.x;
    const int r = blockIdx.x * 16 + (t >> 4);
    const int d0 = (t & 15) * 16;
    const float* src = cb + (size_t)r * 256 + d0;
    __bf16* dst = cbh + (size_t)r * 256 + d0;
    float s = 0.f;
    float4 f[4];
    #pragma unroll
    for (int p = 0; p < 4; p++) f[p] = *(const float4*)(src + p * 4);
    bf16x8 v0, v1;
    #pragma unroll
    for (int p = 0; p < 4; p++) {
        s = fmaf(f[p].x, f[p].x, s); s = fmaf(f[p].y, f[p].y, s);
        s = fmaf(f[p].z, f[p].z, s); s = fmaf(f[p].w, f[p].w, s);
    }
    v0[0]=(__bf16)f[0].x; v0[1]=(__bf16)f[0].y; v0[2]=(__bf16)f[0].z; v0[3]=(__bf16)f[0].w;
    v0[4]=(__bf16)f[1].x; v0[5]=(__bf16)f[1].y; v0[6]=(__bf16)f[1].z; v0[7]=(__bf16)f[1].w;
    v1[0]=(__bf16)f[2].x; v1[1]=(__bf16)f[2].y; v1[2]=(__bf16)f[2].z; v1[3]=(__bf16)f[2].w;
    v1[4]=(__bf16)f[3].x; v1[5]=(__bf16)f[3].y; v1[6]=(__bf16)f[3].z; v1[7]=(__bf16)f[3].w;
    *(bf16x8*)dst = v0;
    *(bf16x8*)(dst + 8) = v1;
    s += __shfl_xor(s, 1, 64);
    s += __shfl_xor(s, 2, 64);
    s += __shfl_xor(s, 4, 64);
    s += __shfl_xor(s, 8, 64);
    if ((t & 15) == 0) sc1[r] = s + 1.0f;
}

// ---------------- Kernel 2: MFMA distance-GEMM + argmin + outputs ----------------
// Block: 128 n-rows x all 1024 codes. 4 waves: each wave all 128 rows (8 row-frags)
// x its own 32 codes (2 frags) of each 128-code chunk. LDS 64 KB z tile [128][256]
// bf16, XOR-swizzled; recycled as argmin scratch, then as chosen-q tile for
// coalesced emit. No barriers in K-loop. 512 blocks = 2/CU, kt-rotated per block.
__global__ __launch_bounds__(256, 2) void vq_mfma(const float* __restrict__ z,
                                                  const __bf16* __restrict__ cbh,
                                                  const float* __restrict__ sc1,
                                                  float* __restrict__ out) {
    __shared__ __align__(16) __bf16 z_s[128 * 256];   // 65536 B
    __shared__ float red_s[4];

    const int t    = threadIdx.x;
    const int lane = t & 63;
    const int w    = t >> 6;
    const int m16  = lane & 15;
    const int q4   = lane >> 4;
    const int wc   = w << 5;              // wave's code offset within a 128-chunk
    const int blk  = blockIdx.x;
    const int b    = blk >> 3;
    const int hw0  = (blk & 7) << 7;
    const int n0   = blk << 7;
    const int kt0  = (blk & 7) << 7;      // rotated code-sweep start (desync L2 streams)

    // B preload: first chunk's dc=0 frag pair, in flight during phase A
    bf16x8 bb[2];
    {
        const __bf16* bp = cbh + (size_t)(kt0 + wc + m16) * 256 + q4 * 8;
        bb[0] = *(const bf16x8*)bp;
        bb[1] = *(const bf16x8*)(bp + 4096);
    }

    // ---- phase A: stage z (fp32 global, float4 along hw) -> bf16 LDS [n][d]; sum z^2
    float lz = 0.f;
    {
        const int rg    = (t & 31) * 4;       // 4-row group (128 rows total)
        const int dbase = (t >> 5) * 32;      // 32 d's per thread (8 groups)
        const float* zp = z + (size_t)b * 262144 + hw0 + rg;
        #pragma unroll
        for (int batch = 0; batch < 4; batch++) {
            float4 f[8];
            #pragma unroll
            for (int j = 0; j < 8; j++)
                f[j] = *(const float4*)(zp + (size_t)(dbase + batch * 8 + j) * 1024);
            const float* fp = (const float*)f;
            #pragma unroll
            for (int r = 0; r < 4; r++) {
                bf16x8 v;
                #pragma unroll
                for (int j = 0; j < 8; j++) {
                    float x = fp[j * 4 + r];
                    lz = fmaf(x, x, lz);
                    v[j] = (__bf16)x;
                }
                const int row = rg + r;
                const int gs  = ((dbase >> 3) + batch) ^ (row & 7);
                *(bf16x8*)&z_s[row * 256 + gs * 8] = v;
            }
        }
    }
    __syncthreads();

    // ---- GEMM + packed-uint running argmin (no barriers in K-loop)
    unsigned int best[32];
    #pragma unroll
    for (int i = 0; i < 32; i++) best[i] = 0xFFFFFFFFu;

    #pragma unroll 1
    for (int it = 0; it < 8; it++) {
        const int kt  = (kt0 + (it << 7)) & 1023;
        const int ktn = (kt0 + (((it + 1) & 7) << 7)) & 1023;
        // per-chunk code norms (+1) and packed indices — hidden under MFMAs
        int   kcv[2];
        float sck[2];
        #pragma unroll
        for (int j = 0; j < 2; j++) {
            kcv[j] = kt + wc + j * 16 + m16;
            sck[j] = sc1[kcv[j]];
        }
        const __bf16* bc  = cbh + (size_t)(kt + wc + m16) * 256 + q4 * 8;
        const __bf16* bnx = cbh + (size_t)(ktn + wc + m16) * 256 + q4 * 8;

        f32x4 acc[8][2];
        #pragma unroll
        for (int i = 0; i < 8; i++)
            #pragma unroll
            for (int j = 0; j < 2; j++) acc[i][j] = (f32x4){0.f, 0.f, 0.f, 0.f};

        #pragma unroll
        for (int dcs = 0; dcs < 8; dcs++) {
            const int dc = dcs * 32;
            // B prefetch 1 iteration ahead (next kt's dc=0 on the last step)
            bf16x8 bn[2];
            const __bf16* bp = (dcs < 7) ? (bc + dc + 32) : bnx;
            bn[0] = *(const bf16x8*)bp;
            bn[1] = *(const bf16x8*)(bp + 4096);

            // A frags in-place (compiler schedules; R4 proved manual prefetch null)
            const int gs = ((dc >> 3) + q4) ^ (m16 & 7);
            #pragma unroll
            for (int i = 0; i < 8; i++) {
                bf16x8 a = *(const bf16x8*)&z_s[(i * 16 + m16) * 256 + gs * 8];
                acc[i][0] = __builtin_amdgcn_mfma_f32_16x16x32_bf16(a, bb[0], acc[i][0], 0, 0, 0);
                acc[i][1] = __builtin_amdgcn_mfma_f32_16x16x32_bf16(a, bb[1], acc[i][1], 0, 0, 0);
            }

            bb[0] = bn[0];
            bb[1] = bn[1];
        }

        // packed argmin: score = 1 + ||c||^2 - 2 z.c  > 0 always
        #pragma unroll
        for (int j = 0; j < 2; j++) {
            #pragma unroll
            for (int i = 0; i < 8; i++)
                #pragma unroll
                for (int r = 0; r < 4; r++) {
                    float v3 = fmaf(-2.f, acc[i][j][r], sck[j]);
                    unsigned int key = (__float_as_uint(v3) & 0xFFFFFC00u) | (unsigned int)kcv[j];
                    int pos = i * 4 + r;
                    best[pos] = min(best[pos], key);
                }
        }
    }

    // ---- intra-wave min across the 16 col-lanes
    #pragma unroll
    for (int pos = 0; pos < 32; pos++) {
        unsigned int k = best[pos];
        #pragma unroll
        for (int off = 1; off < 16; off <<= 1)
            k = min(k, (unsigned int)__shfl_xor((int)k, off, 64));
        best[pos] = k;
    }
    __syncthreads();              // all z_s reads done -> z_s becomes scratch

    // ---- cross-wave combine in recycled z_s
    // ks[0..512): key[wave][row] (each wave owns a distinct code quarter);
    // ks[512..640): chosen k
    unsigned int* ks = (unsigned int*)z_s;
    if (m16 == 0) {
        #pragma unroll
        for (int pos = 0; pos < 32; pos++) {
            int i = pos >> 2, r = pos & 3;
            int row = i * 16 + q4 * 4 + r;
            ks[w * 128 + row] = best[pos];
        }
    }
    __syncthreads();
    if (t < 128) {
        unsigned int key = min(min(ks[t], ks[128 + t]), min(ks[256 + t], ks[384 + t]));
        int kf = (int)(key & 1023u);
        ks[512 + t] = (unsigned int)kf;
        out[IDX_OFF + n0 + t] = (float)kf;
        lz += __uint_as_float(key & 0xFFFFFC00u) - 1.0f;   // best score (unshifted)
    }
    {
        float s = lz;
        #pragma unroll
        for (int off = 1; off < 64; off <<= 1) s += __shfl_xor(s, off, 64);
        if (lane == 0) red_s[w] = s;
    }
    __syncthreads();              // ks[512..640) and red_s visible
    if (t == 0)
        atomicAdd(out + LOSS_OFF, 1.25f * ((red_s[0] + red_s[1]) + (red_s[2] + red_s[3])));

    // ---- stage chosen codebook rows into z_s, then coalesced emit
    const int qrow = t >> 1;              // 0..127
    const int qoff = (t & 1) * 128;       // d offset 0/128
    const int myk  = (int)ks[512 + qrow];
    __syncthreads();              // everyone read their k; safe to overwrite z_s
    {
        const __bf16* qp = cbh + (size_t)myk * 256 + qoff;
        #pragma unroll
        for (int p = 0; p < 16; p++) {
            bf16x8 v = *(const bf16x8*)(qp + p * 8);
            int gs = ((qoff >> 3) + p) ^ (qrow & 7);
            *(bf16x8*)&z_s[qrow * 256 + gs * 8] = v;
        }
    }
    __syncthreads();
    {
        const int nl   = t & 127;
        const int dseg = t >> 7;          // 0 or 1 -> d 0..127 / 128..255
        float* op = out + (size_t)(b * 256 + dseg * 128) * 1024 + hw0 + nl;
        #pragma unroll
        for (int p = 0; p < 16; p++) {
            int gs = (dseg * 16 + p) ^ (nl & 7);
            bf16x8 v = *(const bf16x8*)&z_s[nl * 256 + gs * 8];
            #pragma unroll
            for (int j = 0; j < 8; j++)
                op[(size_t)(p * 8 + j) * 1024] = (float)v[j];
        }
    }
}

extern "C" void kernel_launch(void* const* d_in, const int* in_sizes, int n_in,
                              void* d_out, int out_size, void* d_ws, size_t ws_size,
                              hipStream_t stream) {
    const float* z  = (const float*)d_in[0];   // 16777216
    const float* cb = (const float*)d_in[1];   // 262144
    float* out = (float*)d_out;

    float*  sc1 = (float*)d_ws;                        // 1024 f  (1 + ||c||^2)
    __bf16* cbh = (__bf16*)((char*)d_ws + 8192);       // 512 KB bf16 codebook

    hipMemsetAsync(out + LOSS_OFF, 0, sizeof(float), stream);   // capture-safe
    vq_prep<<<64, 256, 0, stream>>>(cb, cbh, sc1);
    vq_mfma<<<512, 256, 0, stream>>>(z, cbh, sc1, out);
}

// Round 6
// 163.311 us; speedup vs baseline: 1.5281x; 1.5281x over previous
//
#include <hip/hip_runtime.h>

// VQ embedding, bf16-MFMA, packed uint argmin.
// z: (B=64, D=256, H=32, W=32) fp32; codebook: (K=1024, D=256) fp32.
// argmin_k ||z_n - c_k||^2 = argmin_k (1 + ||c_k||^2 - 2 z.c_k)   [shift keeps score > 0]
// Packed key: (float_bits(score) & 0xFFFFFC00) | k  -> uint min = argmin w/ first-index ties.
// Outputs (flat fp32): st[16777216] = chosen codebook row, indices[65536] as float,
// loss = 1.25 * (sum z^2 + sum (best_score - 1)).
//
// R6: B-stream was 16 scattered 64B lines per wave-load (code-row stride 512 B);
// per-CU B rate sat at ~10 B/cyc = the scattered-request ceiling (R2/R4 nulls show
// TLP/pipelining don't move it). Fix: SECOND codebook copy in fragment-major order —
// cbf[(tile16*8 + chunk32)*512 + (m16*4+q4)*8] — so each wave B-load is one dense
// 1 KB burst with compile-time chunk offsets. Structure otherwise = R3/R4 frontier:
// 64-row tile, codes-x4 no-dup waves, acc[4][2], in-place A, 1-deep B prefetch.
// Row-major cbh kept for the emit gather.

#define IDX_OFF  16777216
#define LOSS_OFF 16842752

typedef __bf16 bf16x8 __attribute__((ext_vector_type(8)));
typedef float  f32x4  __attribute__((ext_vector_type(4)));

// ------- Kernel 1: cb fp32 -> bf16 row-major + frag-major copies + (1 + ||c||^2) -------
__global__ __launch_bounds__(256) void vq_prep(const float* __restrict__ cb,
                                               __bf16* __restrict__ cbh,
                                               __bf16* __restrict__ cbf,
                                               float* __restrict__ sc1) {
    const int t = threadIdx.x;
    const int r = blockIdx.x * 16 + (t >> 4);
    const int d0 = (t & 15) * 16;
    const float* src = cb + (size_t)r * 256 + d0;
    __bf16* dst = cbh + (size_t)r * 256 + d0;
    float s = 0.f;
    float4 f[4];
    #pragma unroll
    for (int p = 0; p < 4; p++) f[p] = *(const float4*)(src + p * 4);
    bf16x8 v0, v1;
    #pragma unroll
    for (int p = 0; p < 4; p++) {
        s = fmaf(f[p].x, f[p].x, s); s = fmaf(f[p].y, f[p].y, s);
        s = fmaf(f[p].z, f[p].z, s); s = fmaf(f[p].w, f[p].w, s);
    }
    v0[0]=(__bf16)f[0].x; v0[1]=(__bf16)f[0].y; v0[2]=(__bf16)f[0].z; v0[3]=(__bf16)f[0].w;
    v0[4]=(__bf16)f[1].x; v0[5]=(__bf16)f[1].y; v0[6]=(__bf16)f[1].z; v0[7]=(__bf16)f[1].w;
    v1[0]=(__bf16)f[2].x; v1[1]=(__bf16)f[2].y; v1[2]=(__bf16)f[2].z; v1[3]=(__bf16)f[2].w;
    v1[4]=(__bf16)f[3].x; v1[5]=(__bf16)f[3].y; v1[6]=(__bf16)f[3].z; v1[7]=(__bf16)f[3].w;
    *(bf16x8*)dst = v0;
    *(bf16x8*)(dst + 8) = v1;
    // frag-major: tile = r>>4, chunk = d0>>5, lane slot = (r&15)*4 + ((d0>>3)&3)
    {
        const int slot = ((r >> 4) * 8 + (d0 >> 5)) * 512 + ((r & 15) * 4 + ((d0 >> 3) & 3)) * 8;
        *(bf16x8*)&cbf[slot]     = v0;
        *(bf16x8*)&cbf[slot + 8] = v1;
    }
    s += __shfl_xor(s, 1, 64);
    s += __shfl_xor(s, 2, 64);
    s += __shfl_xor(s, 4, 64);
    s += __shfl_xor(s, 8, 64);
    if ((t & 15) == 0) sc1[r] = s + 1.0f;
}

// ---------------- Kernel 2: MFMA distance-GEMM + argmin + outputs ----------------
// Block: 64 n-rows x all 1024 codes. 4 waves: each wave all 64 rows (4 row-frags)
// x its own 32 codes (2 frags) of each 128-code chunk. LDS 32 KB z tile [64][256]
// bf16, XOR-swizzled; recycled as argmin scratch, then as chosen-q tile for
// coalesced emit. No barriers in K-loop. 1024 blocks, kt-rotated per block.
__global__ __launch_bounds__(256, 2) void vq_mfma(const float* __restrict__ z,
                                                  const __bf16* __restrict__ cbh,
                                                  const __bf16* __restrict__ cbf,
                                                  const float* __restrict__ sc1,
                                                  float* __restrict__ out) {
    __shared__ __align__(16) __bf16 z_s[64 * 256];    // 32768 B
    __shared__ float red_s[4];

    const int t    = threadIdx.x;
    const int lane = t & 63;
    const int w    = t >> 6;
    const int m16  = lane & 15;
    const int q4   = lane >> 4;
    const int wc   = w << 5;              // wave's code offset within a 128-chunk
    const int lidx = m16 * 4 + q4;        // frag-major lane slot
    const int blk  = blockIdx.x;
    const int b    = blk >> 4;
    const int hw0  = (blk & 15) << 6;
    const int n0   = blk << 6;
    const int kt0  = (blk & 3) << 8;      // rotated code-sweep start (desync L2 streams)

    // B preload: first chunk's frag pair (dense 1 KB burst/wave), in flight during phase A
    bf16x8 bb[2];
    {
        const __bf16* bp = cbf + (size_t)((kt0 + wc) >> 4) * 4096 + lidx * 8;
        bb[0] = *(const bf16x8*)bp;
        bb[1] = *(const bf16x8*)(bp + 4096);
    }

    // ---- phase A: stage z (fp32 global, float4 along hw) -> bf16 LDS [n][d]; sum z^2
    float lz = 0.f;
    {
        const int rg    = (t & 15) * 4;       // 4-row group
        const int dbase = (t >> 4) * 16;      // 16 d's per thread
        const float* zp = z + (size_t)b * 262144 + hw0 + rg;
        #pragma unroll
        for (int batch = 0; batch < 2; batch++) {
            float4 f[8];
            #pragma unroll
            for (int j = 0; j < 8; j++)
                f[j] = *(const float4*)(zp + (size_t)(dbase + batch * 8 + j) * 1024);
            const float* fp = (const float*)f;
            #pragma unroll
            for (int r = 0; r < 4; r++) {
                bf16x8 v;
                #pragma unroll
                for (int j = 0; j < 8; j++) {
                    float x = fp[j * 4 + r];
                    lz = fmaf(x, x, lz);
                    v[j] = (__bf16)x;
                }
                const int row = rg + r;
                const int gs  = ((t >> 4) * 2 + batch) ^ (row & 7);
                *(bf16x8*)&z_s[row * 256 + gs * 8] = v;
            }
        }
    }
    __syncthreads();

    // ---- GEMM + packed-uint running argmin (no barriers in K-loop)
    unsigned int best[16];
    #pragma unroll
    for (int i = 0; i < 16; i++) best[i] = 0xFFFFFFFFu;

    #pragma unroll 1
    for (int it = 0; it < 8; it++) {
        const int kt  = (kt0 + (it << 7)) & 1023;
        const int ktn = (kt0 + (((it + 1) & 7) << 7)) & 1023;
        // per-chunk code norms (+1) and packed indices — hidden under MFMAs
        int   kcv[2];
        float sck[2];
        #pragma unroll
        for (int j = 0; j < 2; j++) {
            kcv[j] = kt + wc + j * 16 + m16;
            sck[j] = sc1[kcv[j]];
        }
        // frag-major bases: tile stride 4096 elems, chunk stride 512 elems (compile-time)
        const __bf16* bt  = cbf + (size_t)((kt  + wc) >> 4) * 4096 + lidx * 8;
        const __bf16* btn = cbf + (size_t)((ktn + wc) >> 4) * 4096 + lidx * 8;

        f32x4 acc[4][2];
        #pragma unroll
        for (int i = 0; i < 4; i++)
            #pragma unroll
            for (int j = 0; j < 2; j++) acc[i][j] = (f32x4){0.f, 0.f, 0.f, 0.f};

        #pragma unroll
        for (int dcs = 0; dcs < 8; dcs++) {
            const int dc = dcs * 32;
            // B prefetch 1 chunk ahead (next kt's chunk 0 on the last step)
            bf16x8 bn[2];
            const __bf16* bp = (dcs < 7) ? (bt + (dcs + 1) * 512) : btn;
            bn[0] = *(const bf16x8*)bp;
            bn[1] = *(const bf16x8*)(bp + 4096);

            // A frags in-place (compiler schedules fine per R4 null)
            const int gs = ((dc >> 3) + q4) ^ (m16 & 7);
            #pragma unroll
            for (int i = 0; i < 4; i++) {
                bf16x8 a = *(const bf16x8*)&z_s[(i * 16 + m16) * 256 + gs * 8];
                acc[i][0] = __builtin_amdgcn_mfma_f32_16x16x32_bf16(a, bb[0], acc[i][0], 0, 0, 0);
                acc[i][1] = __builtin_amdgcn_mfma_f32_16x16x32_bf16(a, bb[1], acc[i][1], 0, 0, 0);
            }

            bb[0] = bn[0];
            bb[1] = bn[1];
        }

        // packed argmin: score = 1 + ||c||^2 - 2 z.c  > 0 always
        #pragma unroll
        for (int j = 0; j < 2; j++) {
            #pragma unroll
            for (int i = 0; i < 4; i++)
                #pragma unroll
                for (int r = 0; r < 4; r++) {
                    float v3 = fmaf(-2.f, acc[i][j][r], sck[j]);
                    unsigned int key = (__float_as_uint(v3) & 0xFFFFFC00u) | (unsigned int)kcv[j];
                    int pos = i * 4 + r;
                    best[pos] = min(best[pos], key);
                }
        }
    }

    // ---- intra-wave min across the 16 col-lanes
    #pragma unroll
    for (int pos = 0; pos < 16; pos++) {
        unsigned int k = best[pos];
        #pragma unroll
        for (int off = 1; off < 16; off <<= 1)
            k = min(k, (unsigned int)__shfl_xor((int)k, off, 64));
        best[pos] = k;
    }
    __syncthreads();              // all z_s reads done -> z_s becomes scratch

    // ---- cross-wave combine in recycled z_s
    // ks[0..256): key[wave][row] (each wave owns a distinct code quarter);
    // ks[256..320): chosen k
    unsigned int* ks = (unsigned int*)z_s;
    if (m16 == 0) {
        #pragma unroll
        for (int pos = 0; pos < 16; pos++) {
            int i = pos >> 2, r = pos & 3;
            int row = i * 16 + q4 * 4 + r;
            ks[w * 64 + row] = best[pos];
        }
    }
    __syncthreads();
    if (t < 64) {
        unsigned int key = min(min(ks[t], ks[64 + t]), min(ks[128 + t], ks[192 + t]));
        int kf = (int)(key & 1023u);
        ks[256 + t] = (unsigned int)kf;
        out[IDX_OFF + n0 + t] = (float)kf;
        lz += __uint_as_float(key & 0xFFFFFC00u) - 1.0f;   // best score (unshifted)
    }
    {
        float s = lz;
        #pragma unroll
        for (int off = 1; off < 64; off <<= 1) s += __shfl_xor(s, off, 64);
        if (lane == 0) red_s[w] = s;
    }
    __syncthreads();              // ks[256..320) and red_s visible
    if (t == 0)
        atomicAdd(out + LOSS_OFF, 1.25f * ((red_s[0] + red_s[1]) + (red_s[2] + red_s[3])));

    // ---- stage chosen codebook rows into z_s, then coalesced emit
    const int qrow = t >> 2;              // 0..63
    const int qoff = (t & 3) * 64;        // d offset 0/64/128/192
    const int myk  = (int)ks[256 + qrow];
    __syncthreads();              // everyone read their k; safe to overwrite z_s
    {
        const __bf16* qp = cbh + (size_t)myk * 256 + qoff;
        #pragma unroll
        for (int p = 0; p < 8; p++) {
            bf16x8 v = *(const bf16x8*)(qp + p * 8);
            int gs = ((qoff >> 3) + p) ^ (qrow & 7);
            *(bf16x8*)&z_s[qrow * 256 + gs * 8] = v;
        }
    }
    __syncthreads();
    {
        const int nl   = t & 63;
        const int dseg = t >> 6;
        float* op = out + (size_t)(b * 256 + dseg * 64) * 1024 + hw0 + nl;
        #pragma unroll
        for (int p = 0; p < 8; p++) {
            int gs = (dseg * 8 + p) ^ (nl & 7);
            bf16x8 v = *(const bf16x8*)&z_s[nl * 256 + gs * 8];
            #pragma unroll
            for (int j = 0; j < 8; j++)
                op[(size_t)(p * 8 + j) * 1024] = (float)v[j];
        }
    }
}

extern "C" void kernel_launch(void* const* d_in, const int* in_sizes, int n_in,
                              void* d_out, int out_size, void* d_ws, size_t ws_size,
                              hipStream_t stream) {
    const float* z  = (const float*)d_in[0];   // 16777216
    const float* cb = (const float*)d_in[1];   // 262144
    float* out = (float*)d_out;

    float*  sc1 = (float*)d_ws;                             // 1024 f  (1 + ||c||^2)
    __bf16* cbh = (__bf16*)((char*)d_ws + 8192);            // 512 KB bf16 codebook (row-major)
    __bf16* cbf = (__bf16*)((char*)d_ws + 8192 + 524288);   // 512 KB bf16 codebook (frag-major)

    hipMemsetAsync(out + LOSS_OFF, 0, sizeof(float), stream);   // capture-safe
    vq_prep<<<64, 256, 0, stream>>>(cb, cbh, cbf, sc1);
    vq_mfma<<<1024, 256, 0, stream>>>(z, cbh, cbf, sc1, out);
}